// Round 21
// baseline (123.214 us; speedup 1.0000x reference)
//
#include <hip/hip_runtime.h>
#include <stdint.h>

#define KD 4096
#define ND 4096
#define BK 128
#define NT 32            // K-tiles

typedef float f32x4 __attribute__((ext_vector_type(4)));
typedef int   i32x4 __attribute__((ext_vector_type(4)));

#define GLDS16(gp, lp) \
    __builtin_amdgcn_global_load_lds((const __attribute__((address_space(1))) void*)(gp), \
                                     (__attribute__((address_space(3))) void*)(lp), 16, 0, 0)

// ---------------------------------------------------------------------------
// Single prep launch (6144 blocks) — R20 verbatim (prep ~19us vs ~21us BW
// floor: done):
//  blocks [0,4096): xq — per-row x fp32 -> i8, sx[r] = rowabsmax/127.
//  blocks [4096,6144): sc+wq fused — one block per packed row o.
// ---------------------------------------------------------------------------
__global__ void prep_kernel(const float* __restrict__ x,
                            const int* __restrict__ Wq,
                            const float* __restrict__ scale,
                            const float* __restrict__ zero,
                            int8_t* __restrict__ xi,
                            float* __restrict__ sx,
                            int8_t* __restrict__ Wi,
                            float* __restrict__ sc) {
    const int t = threadIdx.x;
    if (blockIdx.x >= 4096) {
        const int o = blockIdx.x - 4096;           // 0..2047
        __shared__ float shs[4][64];               // s_hi, z_hi, s_lo, z_lo
        __shared__ float shsc[2];
        if (t < 128) {
            const int half = t >> 6;               // 0 = col o, 1 = col o+2048
            const int g = t & 63;
            const int col = o + half * 2048;
            float s = scale[(size_t)col * 64 + g];
            float z = zero[(size_t)col * 64 + g];
            shs[half * 2][g]     = s;
            shs[half * 2 + 1][g] = z;
            float b = s * fmaxf(z, 15.f - z);
#pragma unroll
            for (int off = 32; off; off >>= 1) b = fmaxf(b, __shfl_xor(b, off));
            if (g == 0) {
                float v = fmaxf(b, 1e-20f) * (1.f / 127.f);
                shsc[half] = v;
                sc[col] = v;
            }
        }
        __syncthreads();
        const int g = t >> 2;
        float rch = 1.f / shsc[0], rcl = 1.f / shsc[1];
        float ah = shs[0][g] * rch, bh = -shs[1][g] * ah;
        float al = shs[2][g] * rcl, bl = -shs[3][g] * al;
        const uint4* wp = (const uint4*)(Wq + (size_t)o * KD + t * 16);
        uint4 c0 = wp[0], c1 = wp[1], c2 = wp[2], c3 = wp[3];
        uint32_t vi[16] = {c0.x, c0.y, c0.z, c0.w, c1.x, c1.y, c1.z, c1.w,
                           c2.x, c2.y, c2.z, c2.w, c3.x, c3.y, c3.z, c3.w};
        uint32_t hw[4] = {0,0,0,0}, lw[4] = {0,0,0,0};
#pragma unroll
        for (int e = 0; e < 16; ++e) {
            uint32_t v = vi[e];
            int uh = __float2int_rn(fmaf((float)((v >> 4) & 15u), ah, bh));
            int ul = __float2int_rn(fmaf((float)(v & 15u),        al, bl));
            hw[e >> 2] |= (uint32_t)(uh & 255) << (8 * (e & 3));
            lw[e >> 2] |= (uint32_t)(ul & 255) << (8 * (e & 3));
        }
        uint4 hv = {hw[0], hw[1], hw[2], hw[3]};
        uint4 lv = {lw[0], lw[1], lw[2], lw[3]};
        *(uint4*)(Wi + (size_t)o * KD + t * 16)          = hv;
        *(uint4*)(Wi + (size_t)(o + 2048) * KD + t * 16) = lv;
        return;
    }
    const int r = blockIdx.x;
    const float4* xp = (const float4*)(x + (size_t)r * KD) + t * 4;
    float4 v0 = xp[0], v1 = xp[1], v2 = xp[2], v3 = xp[3];
    float vv[16] = {v0.x, v0.y, v0.z, v0.w, v1.x, v1.y, v1.z, v1.w,
                    v2.x, v2.y, v2.z, v2.w, v3.x, v3.y, v3.z, v3.w};
    float am = 0.f;
#pragma unroll
    for (int j = 0; j < 16; ++j) am = fmaxf(am, fabsf(vv[j]));
#pragma unroll
    for (int off = 32; off; off >>= 1) am = fmaxf(am, __shfl_xor(am, off));
    __shared__ float red[4];
    if ((t & 63) == 0) red[t >> 6] = am;
    __syncthreads();
    am = fmaxf(fmaxf(red[0], red[1]), fmaxf(red[2], red[3]));
    am = fmaxf(am, 1e-20f);
    const float inv = 127.f / am;
    uint32_t w[4];
#pragma unroll
    for (int p = 0; p < 4; ++p) {
        int q0 = __float2int_rn(vv[4*p]     * inv);
        int q1 = __float2int_rn(vv[4*p + 1] * inv);
        int q2 = __float2int_rn(vv[4*p + 2] * inv);
        int q3 = __float2int_rn(vv[4*p + 3] * inv);
        w[p] = (q0 & 255) | ((q1 & 255) << 8) | ((q2 & 255) << 16) |
               ((uint32_t)(q3 & 255) << 24);
    }
    uint4 pk = {w[0], w[1], w[2], w[3]};
    *(uint4*)(xi + (size_t)r * KD + t * 16) = pk;
    if (t == 0) sx[r] = am / 127.f;
}

// ---------------------------------------------------------------------------
// i8 GEMM = R17/R20 base + window-pipelined ds_reads: ALL 16 frag reads
// (both 64-K windows) issued up front; lgkmcnt(8) releases window 0 (DS
// retires in order — R7-verified); window-1 reads complete UNDER MFQI(w0)
// so the second wait is free. Removes ~1 of the 2 exposed LGKM stalls/tile
// (the measured ~1220 cyc/tile residual over the LDS floor).
// +32 VGPR for the second frag set (64 -> ~96, still <=128 -> 4 waves/SIMD).
// Fences, swizzle, staging byte-identical to R20 (0 conflicts measured).
// ---------------------------------------------------------------------------
#define BAR()  asm volatile("s_barrier" ::: "memory")
#define LGKM(N) do { asm volatile("s_waitcnt lgkmcnt(" #N ")" ::: "memory"); \
                     __builtin_amdgcn_sched_barrier(0); } while (0)
#define VM(N)  asm volatile("s_waitcnt vmcnt(" #N ")" ::: "memory")

#define STI(GP, BUF, MAT, KB) do {                                                    \
    GLDS16((GP) + (size_t)grow * KD + (KB) + sslot * 16,                              \
           ldsb + ((BUF) * 2 + (MAT)) * 32768 + tid * 16);                            \
    GLDS16((GP) + (size_t)(grow + 128) * KD + (KB) + sslot * 16,                      \
           ldsb + ((BUF) * 2 + (MAT)) * 32768 + 16384 + tid * 16);                    \
} while (0)

#define RDI_A(DST, P, KW) do { const uint8_t* _r = ldsb + ((P) * 2 + 0) * 32768;      \
    _Pragma("unroll")                                                                 \
    for (int m = 0; m < 4; ++m)                                                       \
        DST[m] = *(const i32x4*)&_r[(wr * 64 + m * 16 + lr) * 128 + sxw[KW]];         \
} while (0)

#define RDI_B(DST, P, KW) do { const uint8_t* _r = ldsb + ((P) * 2 + 1) * 32768;      \
    _Pragma("unroll")                                                                 \
    for (int n = 0; n < 4; ++n)                                                       \
        DST[n] = *(const i32x4*)&_r[(wc * 64 + n * 16 + lr) * 128 + sxw[KW]];         \
} while (0)

#define MFQI(AS, BS) do {                                                             \
    __builtin_amdgcn_s_setprio(1);                                                    \
    _Pragma("unroll")                                                                 \
    for (int m = 0; m < 4; ++m)                                                       \
    _Pragma("unroll")                                                                 \
    for (int n = 0; n < 4; ++n)                                                       \
        acc[m][n] = __builtin_amdgcn_mfma_i32_16x16x64_i8(                            \
            AS[m], BS[n], acc[m][n], 0, 0, 0);                                        \
    __builtin_amdgcn_s_setprio(0);                                                    \
} while (0)

__global__ __launch_bounds__(1024, 4)
void gemm_kernel(const int8_t* __restrict__ xi,
                 const int8_t* __restrict__ Wi,
                 const float* __restrict__ sx,
                 const float* __restrict__ sc,
                 float* __restrict__ C) {
    __shared__ uint8_t ldsb[131072];  // 128 KiB: [2 buf][2 mat][256][128]

    const int tid  = threadIdx.x;
    const int wave = tid >> 6;
    const int lane = tid & 63;
    const int wr = wave >> 2;                  // 0..3 (M)
    const int wc = wave & 3;                   // 0..3 (N)
    const int lr = lane & 15;
    const int ls = lane >> 4;
    const int xk = (lr >> 1) & 7;
    int sxw[2];
    sxw[0] = ((0 * 4 + ls) ^ xk) * 16;         // window-0 swizzled byte slot
    sxw[1] = ((1 * 4 + ls) ^ xk) * 16;         // window-1
    const int sslot = (tid & 7) ^ ((tid >> 4) & 7);   // stage source pre-swizzle
    const int grow  = tid >> 3;                       // 0..127 staging row

    // XCD-aware swizzle: 256 wgs, 8 XCDs, 32 contiguous tiles per XCD
    int bid = blockIdx.x;
    int wg = (bid & 7) * 32 + (bid >> 3);
    const int bm0 = (wg >> 4) * 256;
    const int bn0 = (wg & 15) * 256;

    const int8_t* Ag = xi + (size_t)bm0 * KD;
    const int8_t* Bg = Wi + (size_t)bn0 * KD;

    i32x4 acc[4][4];
#pragma unroll
    for (int m = 0; m < 4; ++m)
#pragma unroll
        for (int n = 0; n < 4; ++n) {
            i32x4 z = {0, 0, 0, 0};
            acc[m][n] = z;
        }

    i32x4 af0[4], bf0[4], af1[4], bf1[4];

    // prologue: stage tile 0 -> buf0
    STI(Ag, 0, 0, 0);
    STI(Bg, 0, 1, 0);
    VM(0);
    BAR();

#pragma unroll 1
    for (int t = 0; t < NT - 1; ++t) {          // tiles 0..30 (tail = 31)
        const int p = t & 1, q = p ^ 1;
        const int kn = (t + 1) * BK;
        STI(Ag, q, 0, kn);                      // stage tile t+1 (4 gload_lds)
        STI(Bg, q, 1, kn);
        // all 16 ds_read_b128 up front (both windows)
        RDI_A(af0, p, 0); RDI_B(bf0, p, 0);
        RDI_A(af1, p, 1); RDI_B(bf1, p, 1);
        LGKM(8);                                // w0 frags home (in-order DS)
        MFQI(af0, bf0);                         // w1 reads complete underneath
        LGKM(0);                                // free by now
        MFQI(af1, bf1);
        VM(0);                                  // stages ~2 windows deep
        BAR();
    }
    // tail tile 31 (buf1)
    {
        RDI_A(af0, 1, 0); RDI_B(bf0, 1, 0);
        RDI_A(af1, 1, 1); RDI_B(bf1, 1, 1);
        LGKM(8);
        MFQI(af0, bf0);
        LGKM(0);
        MFQI(af1, bf1);
    }

    // epilogue: y = sx[row] * sc[col] * acc.  D layout col=lane&15,
    // row=(lane>>4)*4+r  [m89/m91 — shape-determined, dtype-independent]
    const int r0 = ls * 4;
    float bscale[4];
#pragma unroll
    for (int n = 0; n < 4; ++n)
        bscale[n] = sc[bn0 + wc * 64 + n * 16 + lr];
#pragma unroll
    for (int m = 0; m < 4; ++m) {
        float4 sxv = *(const float4*)(sx + bm0 + wr * 64 + m * 16 + r0);
        float sxa[4] = {sxv.x, sxv.y, sxv.z, sxv.w};
#pragma unroll
        for (int n = 0; n < 4; ++n)
#pragma unroll
            for (int r = 0; r < 4; ++r) {
                int row = bm0 + wr * 64 + m * 16 + r0 + r;
                int col = bn0 + wc * 64 + n * 16 + lr;
                C[(size_t)row * ND + col] = (float)acc[m][n][r] * sxa[r] * bscale[n];
            }
    }
}

extern "C" void kernel_launch(void* const* d_in, const int* in_sizes, int n_in,
                              void* d_out, int out_size, void* d_ws, size_t ws_size,
                              hipStream_t stream) {
    const float* x     = (const float*)d_in[0];
    const int*   Wq    = (const int*)d_in[1];   // uint8 pushed as int32
    const float* scale = (const float*)d_in[2];
    const float* zero  = (const float*)d_in[3];
    float* out = (float*)d_out;

    char* ws = (char*)d_ws;
    int8_t* xi = (int8_t*)(ws);                                   // 16 MB
    int8_t* Wi = (int8_t*)(ws + (size_t)16 * 1024 * 1024);        // 16 MB
    float*  sx = (float*)(ws + (size_t)32 * 1024 * 1024);         // 16 KB
    float*  sc = (float*)(ws + (size_t)32 * 1024 * 1024 + 65536); // 16 KB

    hipLaunchKernelGGL(prep_kernel, dim3(6144), dim3(256), 0, stream,
                       x, Wq, scale, zero, xi, sx, Wi, sc);
    hipLaunchKernelGGL(gemm_kernel, dim3(256), dim3(1024), 0, stream,
                       xi, Wi, sx, sc, out);
}

// Round 22
// 88.577 us; speedup vs baseline: 1.3910x; 1.3910x over previous
//
#include <hip/hip_runtime.h>
#include <stdint.h>

#define KD 4096
#define ND 4096
#define BK 128
#define NT 32            // K-tiles

typedef float f32x4 __attribute__((ext_vector_type(4)));
typedef int   i32x4 __attribute__((ext_vector_type(4)));

#define GLDS16(gp, lp) \
    __builtin_amdgcn_global_load_lds((const __attribute__((address_space(1))) void*)(gp), \
                                     (__attribute__((address_space(3))) void*)(lp), 16, 0, 0)

// ---------------------------------------------------------------------------
// Single prep launch (6144 blocks) — R20 verbatim (prep ~19us vs ~21us BW
// floor: at roofline):
//  blocks [0,4096): xq — per-row x fp32 -> i8, sx[r] = rowabsmax/127.
//  blocks [4096,6144): sc+wq fused — one block per packed row o.
// ---------------------------------------------------------------------------
__global__ void prep_kernel(const float* __restrict__ x,
                            const int* __restrict__ Wq,
                            const float* __restrict__ scale,
                            const float* __restrict__ zero,
                            int8_t* __restrict__ xi,
                            float* __restrict__ sx,
                            int8_t* __restrict__ Wi,
                            float* __restrict__ sc) {
    const int t = threadIdx.x;
    if (blockIdx.x >= 4096) {
        const int o = blockIdx.x - 4096;           // 0..2047
        __shared__ float shs[4][64];               // s_hi, z_hi, s_lo, z_lo
        __shared__ float shsc[2];
        if (t < 128) {
            const int half = t >> 6;               // 0 = col o, 1 = col o+2048
            const int g = t & 63;
            const int col = o + half * 2048;
            float s = scale[(size_t)col * 64 + g];
            float z = zero[(size_t)col * 64 + g];
            shs[half * 2][g]     = s;
            shs[half * 2 + 1][g] = z;
            float b = s * fmaxf(z, 15.f - z);
#pragma unroll
            for (int off = 32; off; off >>= 1) b = fmaxf(b, __shfl_xor(b, off));
            if (g == 0) {
                float v = fmaxf(b, 1e-20f) * (1.f / 127.f);
                shsc[half] = v;
                sc[col] = v;
            }
        }
        __syncthreads();
        const int g = t >> 2;
        float rch = 1.f / shsc[0], rcl = 1.f / shsc[1];
        float ah = shs[0][g] * rch, bh = -shs[1][g] * ah;
        float al = shs[2][g] * rcl, bl = -shs[3][g] * al;
        const uint4* wp = (const uint4*)(Wq + (size_t)o * KD + t * 16);
        uint4 c0 = wp[0], c1 = wp[1], c2 = wp[2], c3 = wp[3];
        uint32_t vi[16] = {c0.x, c0.y, c0.z, c0.w, c1.x, c1.y, c1.z, c1.w,
                           c2.x, c2.y, c2.z, c2.w, c3.x, c3.y, c3.z, c3.w};
        uint32_t hw[4] = {0,0,0,0}, lw[4] = {0,0,0,0};
#pragma unroll
        for (int e = 0; e < 16; ++e) {
            uint32_t v = vi[e];
            int uh = __float2int_rn(fmaf((float)((v >> 4) & 15u), ah, bh));
            int ul = __float2int_rn(fmaf((float)(v & 15u),        al, bl));
            hw[e >> 2] |= (uint32_t)(uh & 255) << (8 * (e & 3));
            lw[e >> 2] |= (uint32_t)(ul & 255) << (8 * (e & 3));
        }
        uint4 hv = {hw[0], hw[1], hw[2], hw[3]};
        uint4 lv = {lw[0], lw[1], lw[2], lw[3]};
        *(uint4*)(Wi + (size_t)o * KD + t * 16)          = hv;
        *(uint4*)(Wi + (size_t)(o + 2048) * KD + t * 16) = lv;
        return;
    }
    const int r = blockIdx.x;
    const float4* xp = (const float4*)(x + (size_t)r * KD) + t * 4;
    float4 v0 = xp[0], v1 = xp[1], v2 = xp[2], v3 = xp[3];
    float vv[16] = {v0.x, v0.y, v0.z, v0.w, v1.x, v1.y, v1.z, v1.w,
                    v2.x, v2.y, v2.z, v2.w, v3.x, v3.y, v3.z, v3.w};
    float am = 0.f;
#pragma unroll
    for (int j = 0; j < 16; ++j) am = fmaxf(am, fabsf(vv[j]));
#pragma unroll
    for (int off = 32; off; off >>= 1) am = fmaxf(am, __shfl_xor(am, off));
    __shared__ float red[4];
    if ((t & 63) == 0) red[t >> 6] = am;
    __syncthreads();
    am = fmaxf(fmaxf(red[0], red[1]), fmaxf(red[2], red[3]));
    am = fmaxf(am, 1e-20f);
    const float inv = 127.f / am;
    uint32_t w[4];
#pragma unroll
    for (int p = 0; p < 4; ++p) {
        int q0 = __float2int_rn(vv[4*p]     * inv);
        int q1 = __float2int_rn(vv[4*p + 1] * inv);
        int q2 = __float2int_rn(vv[4*p + 2] * inv);
        int q3 = __float2int_rn(vv[4*p + 3] * inv);
        w[p] = (q0 & 255) | ((q1 & 255) << 8) | ((q2 & 255) << 16) |
               ((uint32_t)(q3 & 255) << 24);
    }
    uint4 pk = {w[0], w[1], w[2], w[3]};
    *(uint4*)(xi + (size_t)r * KD + t * 16) = pk;
    if (t == 0) sx[r] = am / 127.f;
}

// ---------------------------------------------------------------------------
// i8 GEMM — R17/R20 verbatim (best measured: 67.6 us GEMM, 0 conflicts).
// BK=128, 256x256 tile, 16 waves (4Mx4N of 64x64) @ 1024 thr, one
// VM(0)+BAR per tile, two 64-K windows of {8 ds_read_b128 -> lgkm0 ->
// 16 mfma_i32_16x16x64_i8}. LDS [2buf][2mat][256][128B] = 128 KiB, 8-slot
// swizzle LDS[r][s]=G[r][s^((r>>1)&7)]; integer acc across all K; final
// epilogue y = sx[row]*sc[col]*acc.
// NOTE (R21 lesson): register budget is EXACTLY at the 128/lane cliff
// (acc 64 unified-AGPR + frags 64 VGPR). Any extra register pressure
// (e.g. a second frag set for window prefetch) spills to scratch:
// WRITE_SIZE 67->143 MB, GEMM 67.6->115 us. Do not add registers here.
// ---------------------------------------------------------------------------
#define BAR()  asm volatile("s_barrier" ::: "memory")
#define LGKM0() do { asm volatile("s_waitcnt lgkmcnt(0)" ::: "memory"); \
                     __builtin_amdgcn_sched_barrier(0); } while (0)
#define VM(N)  asm volatile("s_waitcnt vmcnt(" #N ")" ::: "memory")

#define STI(GP, BUF, MAT, KB) do {                                                    \
    GLDS16((GP) + (size_t)grow * KD + (KB) + sslot * 16,                              \
           ldsb + ((BUF) * 2 + (MAT)) * 32768 + tid * 16);                            \
    GLDS16((GP) + (size_t)(grow + 128) * KD + (KB) + sslot * 16,                      \
           ldsb + ((BUF) * 2 + (MAT)) * 32768 + 16384 + tid * 16);                    \
} while (0)

#define RDI_A(P, KW) do { const uint8_t* _r = ldsb + ((P) * 2 + 0) * 32768;           \
    _Pragma("unroll")                                                                 \
    for (int m = 0; m < 4; ++m)                                                       \
        af[m] = *(const i32x4*)&_r[(wr * 64 + m * 16 + lr) * 128 + sxw[KW]];          \
} while (0)

#define RDI_B(P, KW) do { const uint8_t* _r = ldsb + ((P) * 2 + 1) * 32768;           \
    _Pragma("unroll")                                                                 \
    for (int n = 0; n < 4; ++n)                                                       \
        bfr[n] = *(const i32x4*)&_r[(wc * 64 + n * 16 + lr) * 128 + sxw[KW]];         \
} while (0)

#define MFQI() do {                                                                   \
    __builtin_amdgcn_s_setprio(1);                                                    \
    _Pragma("unroll")                                                                 \
    for (int m = 0; m < 4; ++m)                                                       \
    _Pragma("unroll")                                                                 \
    for (int n = 0; n < 4; ++n)                                                       \
        acc[m][n] = __builtin_amdgcn_mfma_i32_16x16x64_i8(                            \
            af[m], bfr[n], acc[m][n], 0, 0, 0);                                       \
    __builtin_amdgcn_s_setprio(0);                                                    \
} while (0)

__global__ __launch_bounds__(1024, 4)
void gemm_kernel(const int8_t* __restrict__ xi,
                 const int8_t* __restrict__ Wi,
                 const float* __restrict__ sx,
                 const float* __restrict__ sc,
                 float* __restrict__ C) {
    __shared__ uint8_t ldsb[131072];  // 128 KiB: [2 buf][2 mat][256][128]

    const int tid  = threadIdx.x;
    const int wave = tid >> 6;
    const int lane = tid & 63;
    const int wr = wave >> 2;                  // 0..3 (M)
    const int wc = wave & 3;                   // 0..3 (N)
    const int lr = lane & 15;
    const int ls = lane >> 4;
    const int xk = (lr >> 1) & 7;
    int sxw[2];
    sxw[0] = ((0 * 4 + ls) ^ xk) * 16;         // window-0 swizzled byte slot
    sxw[1] = ((1 * 4 + ls) ^ xk) * 16;         // window-1
    const int sslot = (tid & 7) ^ ((tid >> 4) & 7);   // stage source pre-swizzle
    const int grow  = tid >> 3;                       // 0..127 staging row

    // XCD-aware swizzle: 256 wgs, 8 XCDs, 32 contiguous tiles per XCD
    int bid = blockIdx.x;
    int wg = (bid & 7) * 32 + (bid >> 3);
    const int bm0 = (wg >> 4) * 256;
    const int bn0 = (wg & 15) * 256;

    const int8_t* Ag = xi + (size_t)bm0 * KD;
    const int8_t* Bg = Wi + (size_t)bn0 * KD;

    i32x4 acc[4][4];
#pragma unroll
    for (int m = 0; m < 4; ++m)
#pragma unroll
        for (int n = 0; n < 4; ++n) {
            i32x4 z = {0, 0, 0, 0};
            acc[m][n] = z;
        }

    i32x4 af[4], bfr[4];

    // prologue: stage tile 0 -> buf0
    STI(Ag, 0, 0, 0);
    STI(Bg, 0, 1, 0);
    VM(0);
    BAR();

#pragma unroll 1
    for (int t = 0; t < NT - 1; ++t) {          // tiles 0..30 (tail = 31)
        const int p = t & 1, q = p ^ 1;
        const int kn = (t + 1) * BK;
        STI(Ag, q, 0, kn);                      // stage tile t+1 (4 gload_lds)
        STI(Bg, q, 1, kn);
        RDI_A(p, 0); RDI_B(p, 0);               // window 0: 8 ds_read_b128
        LGKM0();
        MFQI();                                 // 16 i8 MFMA
        RDI_A(p, 1); RDI_B(p, 1);               // window 1
        LGKM0();
        MFQI();
        VM(0);                                  // stages ~1 tile deep -> free
        BAR();
    }
    // tail tile 31 (buf1)
    {
        RDI_A(1, 0); RDI_B(1, 0);
        LGKM0();
        MFQI();
        RDI_A(1, 1); RDI_B(1, 1);
        LGKM0();
        MFQI();
    }

    // epilogue: y = sx[row] * sc[col] * acc.  D layout col=lane&15,
    // row=(lane>>4)*4+r  [m89/m91 — shape-determined, dtype-independent]
    const int r0 = ls * 4;
    float bscale[4];
#pragma unroll
    for (int n = 0; n < 4; ++n)
        bscale[n] = sc[bn0 + wc * 64 + n * 16 + lr];
#pragma unroll
    for (int m = 0; m < 4; ++m) {
        float4 sxv = *(const float4*)(sx + bm0 + wr * 64 + m * 16 + r0);
        float sxa[4] = {sxv.x, sxv.y, sxv.z, sxv.w};
#pragma unroll
        for (int n = 0; n < 4; ++n)
#pragma unroll
            for (int r = 0; r < 4; ++r) {
                int row = bm0 + wr * 64 + m * 16 + r0 + r;
                int col = bn0 + wc * 64 + n * 16 + lr;
                C[(size_t)row * ND + col] = (float)acc[m][n][r] * sxa[r] * bscale[n];
            }
    }
}

extern "C" void kernel_launch(void* const* d_in, const int* in_sizes, int n_in,
                              void* d_out, int out_size, void* d_ws, size_t ws_size,
                              hipStream_t stream) {
    const float* x     = (const float*)d_in[0];
    const int*   Wq    = (const int*)d_in[1];   // uint8 pushed as int32
    const float* scale = (const float*)d_in[2];
    const float* zero  = (const float*)d_in[3];
    float* out = (float*)d_out;

    char* ws = (char*)d_ws;
    int8_t* xi = (int8_t*)(ws);                                   // 16 MB
    int8_t* Wi = (int8_t*)(ws + (size_t)16 * 1024 * 1024);        // 16 MB
    float*  sx = (float*)(ws + (size_t)32 * 1024 * 1024);         // 16 KB
    float*  sc = (float*)(ws + (size_t)32 * 1024 * 1024 + 65536); // 16 KB

    hipLaunchKernelGGL(prep_kernel, dim3(6144), dim3(256), 0, stream,
                       x, Wq, scale, zero, xi, sx, Wi, sc);
    hipLaunchKernelGGL(gemm_kernel, dim3(256), dim3(1024), 0, stream,
                       xi, Wi, sx, sc, out);
}